// Round 1
// baseline (10343.463 us; speedup 1.0000x reference)
//
#include <hip/hip_runtime.h>

#define EMB 1024
#define NHEADS 16
#define HD 64
#define SEQ 2048
#define BATCH 4

typedef __bf16 bf16x8 __attribute__((ext_vector_type(8)));
typedef float f32x4 __attribute__((ext_vector_type(4)));

__device__ __forceinline__ unsigned short f2bf(float f) {
    union { float f; unsigned int u; } v; v.f = f;
    unsigned int r = (v.u + 0x7FFFu + ((v.u >> 16) & 1u)) >> 16;
    return (unsigned short)r;
}

// ---------------- fp32 -> bf16 elementwise ----------------
__global__ void cvt_bf16(const float4* __restrict__ in, ushort4* __restrict__ out, int n4) {
    int i = blockIdx.x * blockDim.x + threadIdx.x;
    int stride = gridDim.x * blockDim.x;
    for (; i < n4; i += stride) {
        float4 v = in[i];
        ushort4 o;
        o.x = f2bf(v.x); o.y = f2bf(v.y); o.z = f2bf(v.z); o.w = f2bf(v.w);
        out[i] = o;
    }
}

// ---------------- transpose + convert: in [R][C] f32 -> out [C][R] bf16 ----------------
__global__ void transpose_cvt(const float* __restrict__ in, unsigned short* __restrict__ out,
                              int R, int C) {
    __shared__ float tile[32][33];
    int bx = blockIdx.x * 32;  // over C
    int by = blockIdx.y * 32;  // over R
    int tx = threadIdx.x & 31;
    int ty = threadIdx.x >> 5;  // 0..7
    #pragma unroll
    for (int i = 0; i < 32; i += 8)
        tile[ty + i][tx] = in[(size_t)(by + ty + i) * C + bx + tx];
    __syncthreads();
    #pragma unroll
    for (int i = 0; i < 32; i += 8)
        out[(size_t)(bx + ty + i) * R + by + tx] = f2bf(tile[tx][ty + i]);
}

// ---------------- bf16 MFMA GEMM: C[M,N] = A[M,K] * Bt[N,K]^T + bias ----------------
// A row-major bf16, Bt row-major bf16 (i.e. B transposed), C fp32.
// 128x128 block tile, BK=64, 4 waves in 2x2, each wave 64x64 via 4x4 MFMA 16x16x32.
#define BM 128
#define BN 128
#define BK 64
#define LDK 72  // padded row pitch in ushorts (+16B) -> balanced bank groups

__global__ void gemm_bf16(const unsigned short* __restrict__ A,
                          const unsigned short* __restrict__ Bt,
                          const float* __restrict__ bias,
                          float* __restrict__ C,
                          int M, int N, int K) {
    __shared__ unsigned short As[BM * LDK];
    __shared__ unsigned short Bs[BN * LDK];
    const int tid = threadIdx.x;
    const int m0 = blockIdx.y * BM;
    const int n0 = blockIdx.x * BN;
    const int lane = tid & 63;
    const int wave = tid >> 6;
    const int wm = (wave & 1) * 64;
    const int wn = (wave >> 1) * 64;
    const int lm = lane & 15;
    const int quad = lane >> 4;

    f32x4 acc[4][4] = {};

    for (int k0 = 0; k0 < K; k0 += BK) {
        __syncthreads();
        // stage A and B tiles: 1024 chunks of 16B each, 256 threads x 4
        #pragma unroll
        for (int i = 0; i < 4; i++) {
            int c = tid + 256 * i;        // 0..1023
            int row = c >> 3;             // 128 rows, 8 chunks/row
            int col = (c & 7) * 8;        // ushort offset
            uint4 va = *(const uint4*)&A[(size_t)(m0 + row) * K + k0 + col];
            *(uint4*)&As[row * LDK + col] = va;
            uint4 vb = *(const uint4*)&Bt[(size_t)(n0 + row) * K + k0 + col];
            *(uint4*)&Bs[row * LDK + col] = vb;
        }
        __syncthreads();
        #pragma unroll
        for (int kk = 0; kk < 2; kk++) {
            bf16x8 af[4], bfr[4];
            #pragma unroll
            for (int t = 0; t < 4; t++) {
                af[t]  = *(const bf16x8*)&As[(wm + t * 16 + lm) * LDK + kk * 32 + quad * 8];
                bfr[t] = *(const bf16x8*)&Bs[(wn + t * 16 + lm) * LDK + kk * 32 + quad * 8];
            }
            #pragma unroll
            for (int mt = 0; mt < 4; mt++)
                #pragma unroll
                for (int nt = 0; nt < 4; nt++)
                    acc[mt][nt] = __builtin_amdgcn_mfma_f32_16x16x32_bf16(
                        af[mt], bfr[nt], acc[mt][nt], 0, 0, 0);
        }
    }
    // epilogue: C/D layout col=lane&15, row=quad*4+reg
    #pragma unroll
    for (int mt = 0; mt < 4; mt++) {
        #pragma unroll
        for (int nt = 0; nt < 4; nt++) {
            int col = n0 + wn + nt * 16 + lm;
            float bv = bias[col];
            #pragma unroll
            for (int r = 0; r < 4; r++) {
                int row = m0 + wm + mt * 16 + quad * 4 + r;
                C[(size_t)row * N + col] = acc[mt][nt][r] + bv;
            }
        }
    }
}

// ---------------- fp32 flash attention ----------------
// grid: (32 q-blocks, 64 b*h). block 256 threads. 64x64 tiles.
// LDS tiles [64][64] with XOR swizzle on the 16B column chunk: phys_c4 = c4 ^ (row>>2)
__device__ __forceinline__ float4* tile4(float* base, int row, int c4) {
    return (float4*)(base + row * 64 + ((c4 ^ (row >> 2)) << 2));
}

__global__ void attention(const float* __restrict__ qkv,   // [B, S, 3E]
                          unsigned short* __restrict__ outb /* [B, S, E] bf16 */) {
    __shared__ float Qs[64 * 64];
    __shared__ float Ks[64 * 64];  // reused as P after S-compute
    __shared__ float Vs[64 * 64];
    const int tid = threadIdx.x;
    const int tx = tid & 15;   // owns key/dim cols 4tx..4tx+3
    const int ty = tid >> 4;   // owns q rows 4ty..4ty+3
    const int qb = blockIdx.x;
    const int bh = blockIdx.y;
    const int b = bh >> 4;
    const int h = bh & 15;
    const size_t rowstride = 3 * EMB;
    const float* base = qkv + (size_t)b * SEQ * rowstride + h * HD;

    // stage Q tile
    #pragma unroll
    for (int i = 0; i < 4; i++) {
        int c = tid + 256 * i;     // 0..1023
        int row = c >> 4;
        int c4 = c & 15;
        float4 v = *(const float4*)&base[(size_t)(qb * 64 + row) * rowstride + c4 * 4];
        *tile4(Qs, row, c4) = v;
    }

    float m_old[4], l[4], O[4][4];
    #pragma unroll
    for (int i = 0; i < 4; i++) {
        m_old[i] = -3.0e38f; l[i] = 0.f;
        #pragma unroll
        for (int j = 0; j < 4; j++) O[i][j] = 0.f;
    }

    for (int kb = 0; kb <= qb; kb++) {
        __syncthreads();  // previous iter done reading Ks(P)/Vs; Q visible after first
        // stage K and V blocks
        #pragma unroll
        for (int i = 0; i < 4; i++) {
            int c = tid + 256 * i;
            int row = c >> 4;
            int c4 = c & 15;
            const float* kp = &base[(size_t)(kb * 64 + row) * rowstride + EMB + c4 * 4];
            *tile4(Ks, row, c4) = *(const float4*)kp;
            const float* vp = &base[(size_t)(kb * 64 + row) * rowstride + 2 * EMB + c4 * 4];
            *tile4(Vs, row, c4) = *(const float4*)vp;
        }
        __syncthreads();

        // S tile: s[i][j] = Q[4ty+i] . K[4tx+j]
        float s[4][4] = {};
        #pragma unroll
        for (int d4 = 0; d4 < 16; d4++) {
            float4 qv[4], kv[4];
            #pragma unroll
            for (int i = 0; i < 4; i++) qv[i] = *tile4(Qs, 4 * ty + i, d4);
            #pragma unroll
            for (int j = 0; j < 4; j++) kv[j] = *tile4(Ks, 4 * tx + j, d4);
            #pragma unroll
            for (int i = 0; i < 4; i++)
                #pragma unroll
                for (int j = 0; j < 4; j++)
                    s[i][j] += qv[i].x * kv[j].x + qv[i].y * kv[j].y +
                               qv[i].z * kv[j].z + qv[i].w * kv[j].w;
        }
        #pragma unroll
        for (int i = 0; i < 4; i++)
            #pragma unroll
            for (int j = 0; j < 4; j++)
                s[i][j] *= 0.125f;  // 1/sqrt(64)
        if (kb == qb) {
            #pragma unroll
            for (int i = 0; i < 4; i++)
                #pragma unroll
                for (int j = 0; j < 4; j++)
                    if (4 * tx + j > 4 * ty + i) s[i][j] = -10000.0f;
        }

        // online softmax per row
        float p[4][4];
        #pragma unroll
        for (int i = 0; i < 4; i++) {
            float mx = fmaxf(fmaxf(s[i][0], s[i][1]), fmaxf(s[i][2], s[i][3]));
            #pragma unroll
            for (int off = 1; off < 16; off <<= 1) mx = fmaxf(mx, __shfl_xor(mx, off, 64));
            float m_new = fmaxf(m_old[i], mx);
            float alpha = __expf(m_old[i] - m_new);
            float sum = 0.f;
            #pragma unroll
            for (int j = 0; j < 4; j++) { p[i][j] = __expf(s[i][j] - m_new); sum += p[i][j]; }
            #pragma unroll
            for (int off = 1; off < 16; off <<= 1) sum += __shfl_xor(sum, off, 64);
            l[i] = l[i] * alpha + sum;
            #pragma unroll
            for (int j = 0; j < 4; j++) O[i][j] *= alpha;
            m_old[i] = m_new;
        }

        __syncthreads();  // all waves done reading Ks
        // write P into Ks buffer
        #pragma unroll
        for (int i = 0; i < 4; i++) {
            float4 pv = make_float4(p[i][0], p[i][1], p[i][2], p[i][3]);
            *tile4(Ks, 4 * ty + i, tx) = pv;
        }
        __syncthreads();

        // O[i][j] += sum_c P[4ty+i][c] * V[c][4tx+j]
        #pragma unroll
        for (int c4 = 0; c4 < 16; c4++) {
            float pa[4][4];
            #pragma unroll
            for (int i = 0; i < 4; i++) {
                float4 t = *tile4(Ks, 4 * ty + i, c4);
                pa[i][0] = t.x; pa[i][1] = t.y; pa[i][2] = t.z; pa[i][3] = t.w;
            }
            #pragma unroll
            for (int cc = 0; cc < 4; cc++) {
                float4 vv = *tile4(Vs, c4 * 4 + cc, tx);
                #pragma unroll
                for (int i = 0; i < 4; i++) {
                    O[i][0] += pa[i][cc] * vv.x;
                    O[i][1] += pa[i][cc] * vv.y;
                    O[i][2] += pa[i][cc] * vv.z;
                    O[i][3] += pa[i][cc] * vv.w;
                }
            }
        }
    }

    // finalize: normalize, convert to bf16, store
    #pragma unroll
    for (int i = 0; i < 4; i++) {
        float inv = 1.0f / l[i];
        ushort4 o;
        o.x = f2bf(O[i][0] * inv);
        o.y = f2bf(O[i][1] * inv);
        o.z = f2bf(O[i][2] * inv);
        o.w = f2bf(O[i][3] * inv);
        size_t row = (size_t)b * SEQ + qb * 64 + 4 * ty + i;
        *(ushort4*)&outb[row * EMB + h * HD + 4 * tx] = o;
    }
}

extern "C" void kernel_launch(void* const* d_in, const int* in_sizes, int n_in,
                              void* d_out, int out_size, void* d_ws, size_t ws_size,
                              hipStream_t stream) {
    const float* X     = (const float*)d_in[0];  // [4,2048,1024]
    const float* Wqkv  = (const float*)d_in[1];  // [1024,3072]
    const float* bqkv  = (const float*)d_in[2];  // [3072]
    const float* Wproj = (const float*)d_in[3];  // [1024,1024]
    const float* bproj = (const float*)d_in[4];  // [1024]
    float* out = (float*)d_out;

    char* ws = (char*)d_ws;
    unsigned short* Xb     = (unsigned short*)(ws);               // 16,777,216 B
    unsigned short* WqkvT  = (unsigned short*)(ws + 16777216);    //  6,291,456 B
    unsigned short* WprojT = (unsigned short*)(ws + 23068672);    //  2,097,152 B
    float*          qkv    = (float*)(ws + 25165824);             // 100,663,296 B
    unsigned short* attnb  = (unsigned short*)(ws + 125829120);   // 16,777,216 B
    // total ws use: 142,606,336 B

    // 1. X -> bf16
    cvt_bf16<<<2048, 256, 0, stream>>>((const float4*)X, (ushort4*)Xb, (4 * 2048 * 1024) / 4);
    // 2. W^T -> bf16
    transpose_cvt<<<dim3(3072 / 32, 1024 / 32), 256, 0, stream>>>(Wqkv, WqkvT, 1024, 3072);
    transpose_cvt<<<dim3(1024 / 32, 1024 / 32), 256, 0, stream>>>(Wproj, WprojT, 1024, 1024);
    // 3. QKV = X @ Wqkv + b   [8192, 3072] fp32
    gemm_bf16<<<dim3(3072 / BN, 8192 / BM), 256, 0, stream>>>(Xb, WqkvT, bqkv, qkv, 8192, 3072, 1024);
    // 4. causal attention -> bf16 [8192, 1024]
    attention<<<dim3(32, 64), 256, 0, stream>>>(qkv, attnb);
    // 5. out = attn @ Wproj + b   [8192, 1024] fp32
    gemm_bf16<<<dim3(1024 / BN, 8192 / BM), 256, 0, stream>>>(attnb, WprojT, bproj, out, 8192, 1024, 1024);
}

// Round 2
// 410.069 us; speedup vs baseline: 25.2237x; 25.2237x over previous
//
#include <hip/hip_runtime.h>

#define EMB 1024
#define SEQ 2048

typedef __bf16 bf16x8 __attribute__((ext_vector_type(8)));
typedef float f32x4 __attribute__((ext_vector_type(4)));
typedef unsigned short ushort_t;

__device__ __forceinline__ unsigned short f2bf(float f) {
    union { float f; unsigned int u; } v; v.f = f;
    unsigned int r = (v.u + 0x7FFFu + ((v.u >> 16) & 1u)) >> 16;
    return (unsigned short)r;
}

// ---------------- fp32 -> bf16 elementwise ----------------
__global__ void cvt_bf16(const float4* __restrict__ in, ushort4* __restrict__ out, int n4) {
    int i = blockIdx.x * blockDim.x + threadIdx.x;
    int stride = gridDim.x * blockDim.x;
    for (; i < n4; i += stride) {
        float4 v = in[i];
        ushort4 o;
        o.x = f2bf(v.x); o.y = f2bf(v.y); o.z = f2bf(v.z); o.w = f2bf(v.w);
        out[i] = o;
    }
}

// ---------------- transpose + convert: in [R][C] f32 -> out [C][R] bf16 ----------------
__global__ void transpose_cvt(const float* __restrict__ in, unsigned short* __restrict__ out,
                              int R, int C) {
    __shared__ float tile[32][33];
    int bx = blockIdx.x * 32;
    int by = blockIdx.y * 32;
    int tx = threadIdx.x & 31;
    int ty = threadIdx.x >> 5;
    #pragma unroll
    for (int i = 0; i < 32; i += 8)
        tile[ty + i][tx] = in[(size_t)(by + ty + i) * C + bx + tx];
    __syncthreads();
    #pragma unroll
    for (int i = 0; i < 32; i += 8)
        out[(size_t)(bx + ty + i) * R + by + tx] = f2bf(tile[tx][ty + i]);
}

// ---------------- bf16 MFMA GEMM: C[M,N] = A[M,K] * Bt[N,K]^T + bias ----------------
#define BM 128
#define BN 128
#define BK 64
#define LDK 72

template<bool OUT_BF16>
__global__ void gemm_bf16(const unsigned short* __restrict__ A,
                          const unsigned short* __restrict__ Bt,
                          const float* __restrict__ bias,
                          void* __restrict__ Cout,
                          int M, int N, int K) {
    __shared__ unsigned short As[BM * LDK];
    __shared__ unsigned short Bs[BN * LDK];
    const int tid = threadIdx.x;
    const int m0 = blockIdx.y * BM;
    const int n0 = blockIdx.x * BN;
    const int lane = tid & 63;
    const int wave = tid >> 6;
    const int wm = (wave & 1) * 64;
    const int wn = (wave >> 1) * 64;
    const int lm = lane & 15;
    const int quad = lane >> 4;

    f32x4 acc[4][4] = {};

    for (int k0 = 0; k0 < K; k0 += BK) {
        __syncthreads();
        #pragma unroll
        for (int i = 0; i < 4; i++) {
            int c = tid + 256 * i;
            int row = c >> 3;
            int col = (c & 7) * 8;
            uint4 va = *(const uint4*)&A[(size_t)(m0 + row) * K + k0 + col];
            *(uint4*)&As[row * LDK + col] = va;
            uint4 vb = *(const uint4*)&Bt[(size_t)(n0 + row) * K + k0 + col];
            *(uint4*)&Bs[row * LDK + col] = vb;
        }
        __syncthreads();
        #pragma unroll
        for (int kk = 0; kk < 2; kk++) {
            bf16x8 af[4], bfr[4];
            #pragma unroll
            for (int t = 0; t < 4; t++) {
                af[t]  = *(const bf16x8*)&As[(wm + t * 16 + lm) * LDK + kk * 32 + quad * 8];
                bfr[t] = *(const bf16x8*)&Bs[(wn + t * 16 + lm) * LDK + kk * 32 + quad * 8];
            }
            #pragma unroll
            for (int mt = 0; mt < 4; mt++)
                #pragma unroll
                for (int nt = 0; nt < 4; nt++)
                    acc[mt][nt] = __builtin_amdgcn_mfma_f32_16x16x32_bf16(
                        af[mt], bfr[nt], acc[mt][nt], 0, 0, 0);
        }
    }
    #pragma unroll
    for (int mt = 0; mt < 4; mt++) {
        #pragma unroll
        for (int nt = 0; nt < 4; nt++) {
            int col = n0 + wn + nt * 16 + lm;
            float bv = bias[col];
            #pragma unroll
            for (int r = 0; r < 4; r++) {
                int row = m0 + wm + mt * 16 + quad * 4 + r;
                float val = acc[mt][nt][r] + bv;
                if (OUT_BF16)
                    ((unsigned short*)Cout)[(size_t)row * N + col] = f2bf(val);
                else
                    ((float*)Cout)[(size_t)row * N + col] = val;
            }
        }
    }
}

// ---------------- V transpose: qkv bf16 [8192][3072] V-part -> Vt [B*H][64 d][2048 s] ----------------
__global__ void transpose_v(const unsigned short* __restrict__ qkv,
                            unsigned short* __restrict__ vt) {
    __shared__ unsigned short T[64 * 72];
    const int tid = threadIdx.x;
    const int sb = blockIdx.x;   // s tile 0..31
    const int bh = blockIdx.y;   // 0..63
    const int b = bh >> 4;
    const int h = bh & 15;
    const unsigned short* src = qkv + (size_t)(b * SEQ + sb * 64) * 3072 + 2 * EMB + h * 64;
    #pragma unroll
    for (int i = 0; i < 2; i++) {
        int c = tid + 256 * i;
        int row = c >> 3;
        int col = (c & 7) * 8;
        *(uint4*)&T[row * 72 + col] = *(const uint4*)&src[(size_t)row * 3072 + col];
    }
    __syncthreads();
    unsigned short* dst = vt + (size_t)bh * 64 * SEQ + sb * 64;
    #pragma unroll
    for (int i = 0; i < 2; i++) {
        int c = tid + 256 * i;
        int dr = c >> 3;        // d row
        int sc = (c & 7) * 8;   // s col chunk
        unsigned short tmp[8];
        #pragma unroll
        for (int j = 0; j < 8; j++) tmp[j] = T[(sc + j) * 72 + dr];
        *(uint4*)&dst[(size_t)dr * SEQ + sc] = *(uint4*)tmp;
    }
}

// ---------------- MFMA flash attention ----------------
// grid (32 q-tiles, 64 b*h), 256 threads (4 waves x 16 q-rows).
__global__ __launch_bounds__(256, 2)
void attention(const unsigned short* __restrict__ qkv,   // [8192][3072] bf16
               const unsigned short* __restrict__ vt,    // [64][64][2048] bf16
               unsigned short* __restrict__ outb) {      // [8192][1024] bf16
    __shared__ unsigned short Qs[64 * 72];   // reused as P after Q fragments are read
    __shared__ unsigned short Ks[64 * 72];
    __shared__ unsigned short Vs[64 * 72];
    const int tid = threadIdx.x;
    const int lane = tid & 63;
    const int wave = tid >> 6;
    const int lm = lane & 15;
    const int quad = lane >> 4;
    const int qb = blockIdx.x;
    const int bh = blockIdx.y;
    const int b = bh >> 4;
    const int h = bh & 15;

    // stage Q tile (rows qb*64.., cols h*64..h*64+63)
    const unsigned short* qbase = qkv + (size_t)(b * SEQ + qb * 64) * 3072 + h * 64;
    #pragma unroll
    for (int i = 0; i < 2; i++) {
        int c = tid + 256 * i;
        int row = c >> 3;
        int col = (c & 7) * 8;
        *(uint4*)&Qs[row * 72 + col] = *(const uint4*)&qbase[(size_t)row * 3072 + col];
    }
    __syncthreads();
    bf16x8 qf[2];
    #pragma unroll
    for (int kf = 0; kf < 2; kf++)
        qf[kf] = *(const bf16x8*)&Qs[(wave * 16 + lm) * 72 + kf * 32 + quad * 8];
    __syncthreads();   // all waves have their Q frags; Qs reusable as P
    unsigned short* Ps = Qs + wave * 16 * 72;   // per-wave 16x64 slice (pitch 72)

    f32x4 of[4] = {};
    float m_prev[4], l[4];
    #pragma unroll
    for (int r = 0; r < 4; r++) { m_prev[r] = -3.0e38f; l[r] = 0.f; }

    const unsigned short* kbase0 = qkv + (size_t)(b * SEQ) * 3072 + EMB + h * 64;
    const unsigned short* vbase0 = vt + (size_t)bh * 64 * SEQ;

    for (int kb = 0; kb <= qb; kb++) {
        __syncthreads();   // previous iter done reading Ks/Vs
        #pragma unroll
        for (int i = 0; i < 2; i++) {
            int c = tid + 256 * i;
            int row = c >> 3;
            int col = (c & 7) * 8;
            *(uint4*)&Ks[row * 72 + col] =
                *(const uint4*)&kbase0[(size_t)(kb * 64 + row) * 3072 + col];
            *(uint4*)&Vs[row * 72 + col] =
                *(const uint4*)&vbase0[(size_t)row * SEQ + kb * 64 + col];
        }
        __syncthreads();

        // S = Q K^T  (wave's 16 q-rows x 64 k-cols)
        f32x4 sf[4] = {};
        #pragma unroll
        for (int nt = 0; nt < 4; nt++) {
            #pragma unroll
            for (int kf = 0; kf < 2; kf++) {
                bf16x8 bk = *(const bf16x8*)&Ks[(nt * 16 + lm) * 72 + kf * 32 + quad * 8];
                sf[nt] = __builtin_amdgcn_mfma_f32_16x16x32_bf16(qf[kf], bk, sf[nt], 0, 0, 0);
            }
        }
        // scale + causal mask
        #pragma unroll
        for (int nt = 0; nt < 4; nt++)
            #pragma unroll
            for (int r = 0; r < 4; r++)
                sf[nt][r] *= 0.125f;
        if (kb == qb) {
            #pragma unroll
            for (int nt = 0; nt < 4; nt++)
                #pragma unroll
                for (int r = 0; r < 4; r++)
                    if (nt * 16 + lm > wave * 16 + quad * 4 + r) sf[nt][r] = -10000.0f;
        }

        // online softmax (rows = quad*4+r, 16 lanes of this quad hold the cols)
        float p[4][4];
        #pragma unroll
        for (int r = 0; r < 4; r++) {
            float mx = fmaxf(fmaxf(sf[0][r], sf[1][r]), fmaxf(sf[2][r], sf[3][r]));
            #pragma unroll
            for (int off = 1; off < 16; off <<= 1) mx = fmaxf(mx, __shfl_xor(mx, off, 64));
            float mn = fmaxf(m_prev[r], mx);
            float alpha = __expf(m_prev[r] - mn);
            m_prev[r] = mn;
            float sum = 0.f;
            #pragma unroll
            for (int nt = 0; nt < 4; nt++) { p[nt][r] = __expf(sf[nt][r] - mn); sum += p[nt][r]; }
            #pragma unroll
            for (int off = 1; off < 16; off <<= 1) sum += __shfl_xor(sum, off, 64);
            l[r] = l[r] * alpha + sum;
            #pragma unroll
            for (int nt = 0; nt < 4; nt++) of[nt][r] *= alpha;
        }

        // C-layout -> A-layout via per-wave LDS slice (wave-synchronous, no barrier)
        #pragma unroll
        for (int nt = 0; nt < 4; nt++)
            #pragma unroll
            for (int r = 0; r < 4; r++)
                Ps[(quad * 4 + r) * 72 + nt * 16 + lm] = f2bf(p[nt][r]);
        bf16x8 pa[2];
        #pragma unroll
        for (int kf = 0; kf < 2; kf++)
            pa[kf] = *(const bf16x8*)&Ps[lm * 72 + kf * 32 + quad * 8];

        // O += P V   (B operand = Vt rows along k)
        #pragma unroll
        for (int nt = 0; nt < 4; nt++) {
            #pragma unroll
            for (int kf = 0; kf < 2; kf++) {
                bf16x8 bv = *(const bf16x8*)&Vs[(nt * 16 + lm) * 72 + kf * 32 + quad * 8];
                of[nt] = __builtin_amdgcn_mfma_f32_16x16x32_bf16(pa[kf], bv, of[nt], 0, 0, 0);
            }
        }
    }

    // epilogue: normalize, bf16 store
    #pragma unroll
    for (int r = 0; r < 4; r++) {
        float inv = 1.0f / l[r];
        size_t orow = (size_t)(b * SEQ + qb * 64 + wave * 16 + quad * 4 + r);
        #pragma unroll
        for (int nt = 0; nt < 4; nt++)
            outb[orow * EMB + h * 64 + nt * 16 + lm] = f2bf(of[nt][r] * inv);
    }
}

extern "C" void kernel_launch(void* const* d_in, const int* in_sizes, int n_in,
                              void* d_out, int out_size, void* d_ws, size_t ws_size,
                              hipStream_t stream) {
    const float* X     = (const float*)d_in[0];
    const float* Wqkv  = (const float*)d_in[1];
    const float* bqkv  = (const float*)d_in[2];
    const float* Wproj = (const float*)d_in[3];
    const float* bproj = (const float*)d_in[4];
    float* out = (float*)d_out;

    char* ws = (char*)d_ws;
    unsigned short* Xb     = (unsigned short*)(ws);                // 16,777,216 B
    unsigned short* WqkvT  = (unsigned short*)(ws + 16777216);     //  6,291,456 B
    unsigned short* WprojT = (unsigned short*)(ws + 23068672);     //  2,097,152 B
    unsigned short* qkvb   = (unsigned short*)(ws + 25165824);     // 50,331,648 B
    unsigned short* Vt     = (unsigned short*)(ws + 75497472);     // 16,777,216 B
    unsigned short* attnb  = (unsigned short*)(ws + 92274688);     // 16,777,216 B
    // total: 109,051,904 B

    cvt_bf16<<<2048, 256, 0, stream>>>((const float4*)X, (ushort4*)Xb, (4 * 2048 * 1024) / 4);
    transpose_cvt<<<dim3(3072 / 32, 1024 / 32), 256, 0, stream>>>(Wqkv, WqkvT, 1024, 3072);
    transpose_cvt<<<dim3(1024 / 32, 1024 / 32), 256, 0, stream>>>(Wproj, WprojT, 1024, 1024);
    // qkv (bf16) = X @ Wqkv + b
    gemm_bf16<true><<<dim3(3072 / BN, 8192 / BM), 256, 0, stream>>>(
        Xb, WqkvT, bqkv, qkvb, 8192, 3072, 1024);
    // Vt[b*h][d][s]
    transpose_v<<<dim3(32, 64), 256, 0, stream>>>(qkvb, Vt);
    // flash attention -> attnb bf16
    attention<<<dim3(32, 64), 256, 0, stream>>>(qkvb, Vt, attnb);
    // out = attn @ Wproj + b (fp32)
    gemm_bf16<false><<<dim3(1024 / BN, 8192 / BM), 256, 0, stream>>>(
        attnb, WprojT, bproj, out, 8192, 1024, 1024);
}

// Round 3
// 334.326 us; speedup vs baseline: 30.9383x; 1.2266x over previous
//
#include <hip/hip_runtime.h>
#include <hip/hip_bf16.h>

#define EMB 1024
#define SEQ 2048
#define ATT_SCALE 0.18033688011112042f  // 0.125 * log2(e)

typedef __bf16 bf16x8 __attribute__((ext_vector_type(8)));
typedef float f32x4 __attribute__((ext_vector_type(4)));
typedef float f32x16 __attribute__((ext_vector_type(16)));

__device__ __forceinline__ unsigned short f2bf(float f) {
    union { float f; unsigned int u; } v; v.f = f;
    unsigned int r = (v.u + 0x7FFFu + ((v.u >> 16) & 1u)) >> 16;
    return (unsigned short)r;
}

// ---------------- fp32 -> bf16 elementwise ----------------
__global__ void cvt_bf16(const float4* __restrict__ in, ushort4* __restrict__ out, int n4) {
    int i = blockIdx.x * blockDim.x + threadIdx.x;
    int stride = gridDim.x * blockDim.x;
    for (; i < n4; i += stride) {
        float4 v = in[i];
        ushort4 o;
        o.x = f2bf(v.x); o.y = f2bf(v.y); o.z = f2bf(v.z); o.w = f2bf(v.w);
        out[i] = o;
    }
}

// ---------------- transpose + convert: in [R][C] f32 -> out [C][R] bf16 ----------------
__global__ void transpose_cvt(const float* __restrict__ in, unsigned short* __restrict__ out,
                              int R, int C) {
    __shared__ float tile[32][33];
    int bx = blockIdx.x * 32;
    int by = blockIdx.y * 32;
    int tx = threadIdx.x & 31;
    int ty = threadIdx.x >> 5;
    #pragma unroll
    for (int i = 0; i < 32; i += 8)
        tile[ty + i][tx] = in[(size_t)(by + ty + i) * C + bx + tx];
    __syncthreads();
    #pragma unroll
    for (int i = 0; i < 32; i += 8)
        out[(size_t)(bx + ty + i) * R + by + tx] = f2bf(tile[tx][ty + i]);
}

// ---------------- bf16 MFMA GEMM: C[M,N] = A[M,K] * Bt[N,K]^T + bias ----------------
#define BM 128
#define BN 128
#define BK 64
#define LDK 72

template<bool OUT_BF16>
__global__ void gemm_bf16(const unsigned short* __restrict__ A,
                          const unsigned short* __restrict__ Bt,
                          const float* __restrict__ bias,
                          void* __restrict__ Cout,
                          int M, int N, int K) {
    __shared__ unsigned short As[BM * LDK];
    __shared__ unsigned short Bs[BN * LDK];
    const int tid = threadIdx.x;
    const int m0 = blockIdx.y * BM;
    const int n0 = blockIdx.x * BN;
    const int lane = tid & 63;
    const int wave = tid >> 6;
    const int wm = (wave & 1) * 64;
    const int wn = (wave >> 1) * 64;
    const int lm = lane & 15;
    const int quad = lane >> 4;

    f32x4 acc[4][4] = {};

    for (int k0 = 0; k0 < K; k0 += BK) {
        __syncthreads();
        #pragma unroll
        for (int i = 0; i < 4; i++) {
            int c = tid + 256 * i;
            int row = c >> 3;
            int col = (c & 7) * 8;
            uint4 va = *(const uint4*)&A[(size_t)(m0 + row) * K + k0 + col];
            *(uint4*)&As[row * LDK + col] = va;
            uint4 vb = *(const uint4*)&Bt[(size_t)(n0 + row) * K + k0 + col];
            *(uint4*)&Bs[row * LDK + col] = vb;
        }
        __syncthreads();
        #pragma unroll
        for (int kk = 0; kk < 2; kk++) {
            bf16x8 af[4], bfr[4];
            #pragma unroll
            for (int t = 0; t < 4; t++) {
                af[t]  = *(const bf16x8*)&As[(wm + t * 16 + lm) * LDK + kk * 32 + quad * 8];
                bfr[t] = *(const bf16x8*)&Bs[(wn + t * 16 + lm) * LDK + kk * 32 + quad * 8];
            }
            #pragma unroll
            for (int mt = 0; mt < 4; mt++)
                #pragma unroll
                for (int nt = 0; nt < 4; nt++)
                    acc[mt][nt] = __builtin_amdgcn_mfma_f32_16x16x32_bf16(
                        af[mt], bfr[nt], acc[mt][nt], 0, 0, 0);
        }
    }
    #pragma unroll
    for (int mt = 0; mt < 4; mt++) {
        #pragma unroll
        for (int nt = 0; nt < 4; nt++) {
            int col = n0 + wn + nt * 16 + lm;
            float bv = bias[col];
            #pragma unroll
            for (int r = 0; r < 4; r++) {
                int row = m0 + wm + mt * 16 + quad * 4 + r;
                float val = acc[mt][nt][r] + bv;
                if (OUT_BF16)
                    ((unsigned short*)Cout)[(size_t)row * N + col] = f2bf(val);
                else
                    ((float*)Cout)[(size_t)row * N + col] = val;
            }
        }
    }
}

// ---------------- V transpose: qkv bf16 [8192][3072] V-part -> Vt [B*H][64 d][2048 s] ----------------
__global__ void transpose_v(const unsigned short* __restrict__ qkv,
                            unsigned short* __restrict__ vt) {
    __shared__ unsigned short T[64 * 72];
    const int tid = threadIdx.x;
    const int sb = blockIdx.x;
    const int bh = blockIdx.y;
    const int b = bh >> 4;
    const int h = bh & 15;
    const unsigned short* src = qkv + (size_t)(b * SEQ + sb * 64) * 3072 + 2 * EMB + h * 64;
    #pragma unroll
    for (int i = 0; i < 2; i++) {
        int c = tid + 256 * i;
        int row = c >> 3;
        int col = (c & 7) * 8;
        *(uint4*)&T[row * 72 + col] = *(const uint4*)&src[(size_t)row * 3072 + col];
    }
    __syncthreads();
    unsigned short* dst = vt + (size_t)bh * 64 * SEQ + sb * 64;
    #pragma unroll
    for (int i = 0; i < 2; i++) {
        int c = tid + 256 * i;
        int dr = c >> 3;
        int sc = (c & 7) * 8;
        unsigned short tmp[8];
        #pragma unroll
        for (int j = 0; j < 8; j++) tmp[j] = T[(sc + j) * 72 + dr];
        *(uint4*)&dst[(size_t)dr * SEQ + sc] = *(uint4*)tmp;
    }
}

// ---------------- MFMA flash attention, S^T formulation ----------------
// grid (16 q-tiles of 128 rows, 64 b*h), 256 threads = 4 waves x 32 q-rows each.
// S^T = K Q^T via mfma_32x32x16: C col = lane&31 = q, row = c (key idx).
// Softmax per q: in-register over 32 c values + one shfl_xor(32).
// O^T = V^T P^T: same q-per-lane layout -> per-lane scalar alpha rescale.
__global__ __launch_bounds__(256, 3)
void attention(const unsigned short* __restrict__ qkv,   // [8192][3072] bf16
               const unsigned short* __restrict__ vt,    // [64][64][2048] bf16
               unsigned short* __restrict__ outb) {      // [8192][1024] bf16
    __shared__ unsigned short smem[128 * 72];            // Ks | Vs, reused for epilogue
    unsigned short* Ks = smem;
    unsigned short* Vs = smem + 64 * 72;
    const int tid = threadIdx.x;
    const int lane = tid & 63;
    const int wave = tid >> 6;
    const int l31 = lane & 31;
    const int half = lane >> 5;
    const int qt = blockIdx.x;   // 0..15
    const int bh = blockIdx.y;
    const int b = bh >> 4;
    const int h = bh & 15;

    const int qs = qt * 128 + wave * 32 + l31;           // q index within sequence
    const size_t qgrow = (size_t)b * SEQ + qs;

    // Q fragments (B operand): n=q=lane&31, k=d=16*dt+8*half+j. Kept in regs.
    bf16x8 qf[4];
    #pragma unroll
    for (int dt = 0; dt < 4; dt++)
        qf[dt] = *(const bf16x8*)&qkv[qgrow * 3072 + h * 64 + dt * 16 + half * 8];

    f32x16 o[2] = {};
    float m_prev = -1e30f, lsum = 0.f;

    const int nkb = 2 * qt + 2;
    for (int kb = 0; kb < nkb; kb++) {
        __syncthreads();
        #pragma unroll
        for (int i = 0; i < 2; i++) {
            int c = tid + 256 * i;
            int row = c >> 3;
            int ch = (c & 7) * 8;
            *(uint4*)&Ks[row * 72 + ch] =
                *(const uint4*)&qkv[(size_t)(b * SEQ + kb * 64 + row) * 3072 + EMB + h * 64 + ch];
            *(uint4*)&Vs[row * 72 + ch] =
                *(const uint4*)&vt[(size_t)(bh * 64 + row) * SEQ + kb * 64 + ch];
        }
        __syncthreads();

        // S^T: 2 c-tiles x 32 q. A = K rows (m=c), B = Q.
        f32x16 st[2] = {};
        #pragma unroll
        for (int dt = 0; dt < 4; dt++) {
            #pragma unroll
            for (int ct = 0; ct < 2; ct++) {
                bf16x8 kf = *(const bf16x8*)&Ks[(ct * 32 + l31) * 72 + dt * 16 + half * 8];
                st[ct] = __builtin_amdgcn_mfma_f32_32x32x16_bf16(kf, qf[dt], st[ct], 0, 0, 0);
            }
        }

        // causal mask (wave-uniform branch)
        if (kb * 64 + 63 > qt * 128 + wave * 32) {
            #pragma unroll
            for (int ct = 0; ct < 2; ct++)
                #pragma unroll
                for (int r = 0; r < 16; r++) {
                    int cg = kb * 64 + ct * 32 + (r & 3) + 8 * (r >> 2) + 4 * half;
                    if (cg > qs) st[ct][r] = -1e9f;
                }
        }

        // online softmax, per-lane scalar state (q = lane&31)
        float mx = -1e30f;
        #pragma unroll
        for (int r = 0; r < 16; r++) mx = fmaxf(mx, fmaxf(st[0][r], st[1][r]));
        mx = fmaxf(mx, __shfl_xor(mx, 32, 64));
        float m_new = fmaxf(m_prev, mx);
        float alpha = exp2f((m_prev - m_new) * ATT_SCALE);
        float nmc = -m_new * ATT_SCALE;
        float sum = 0.f;
        #pragma unroll
        for (int r = 0; r < 16; r++) {
            st[0][r] = exp2f(__builtin_fmaf(st[0][r], ATT_SCALE, nmc));
            st[1][r] = exp2f(__builtin_fmaf(st[1][r], ATT_SCALE, nmc));
            sum += st[0][r] + st[1][r];
        }
        sum += __shfl_xor(sum, 32, 64);
        lsum = lsum * alpha + sum;
        m_prev = m_new;
        #pragma unroll
        for (int r = 0; r < 16; r++) { o[0][r] *= alpha; o[1][r] *= alpha; }

        // pack P to bf16 pairs: pk[t][i] = (p[2i] lo, p[2i+1] hi)
        unsigned int pk[2][8];
        #pragma unroll
        for (int t = 0; t < 2; t++)
            #pragma unroll
            for (int i = 0; i < 8; i++) {
                __hip_bfloat162 pb = __float22bfloat162_rn(float2{st[t][2 * i], st[t][2 * i + 1]});
                union { __hip_bfloat162 b; unsigned int u; } cv; cv.b = pb;
                pk[t][i] = cv.u;
            }

        // P^T B-frags via half-wave exchange; O^T += V^T P^T
        #pragma unroll
        for (int kt = 0; kt < 4; kt++) {
            const int t = kt >> 1, e = kt & 1;
            unsigned int own0 = half ? pk[t][4 * e + 2] : pk[t][4 * e + 0];
            unsigned int own1 = half ? pk[t][4 * e + 3] : pk[t][4 * e + 1];
            unsigned int snd0 = half ? pk[t][4 * e + 0] : pk[t][4 * e + 2];
            unsigned int snd1 = half ? pk[t][4 * e + 1] : pk[t][4 * e + 3];
            unsigned int rcv0 = (unsigned int)__shfl_xor((int)snd0, 32, 64);
            unsigned int rcv1 = (unsigned int)__shfl_xor((int)snd1, 32, 64);
            union { uint4 u; bf16x8 v; } pf;
            pf.u.x = half ? rcv0 : own0;
            pf.u.y = half ? rcv1 : own1;
            pf.u.z = half ? own0 : rcv0;
            pf.u.w = half ? own1 : rcv1;
            #pragma unroll
            for (int dt = 0; dt < 2; dt++) {
                bf16x8 vf = *(const bf16x8*)&Vs[(dt * 32 + l31) * 72 + kt * 16 + half * 8];
                o[dt] = __builtin_amdgcn_mfma_f32_32x32x16_bf16(vf, pf.v, o[dt], 0, 0, 0);
            }
        }
    }

    // epilogue: O^T (d rows, q cols) -> LDS [q][d] -> coalesced bf16 store
    __syncthreads();
    float inv = 1.0f / lsum;
    #pragma unroll
    for (int dt = 0; dt < 2; dt++)
        #pragma unroll
        for (int r = 0; r < 16; r++) {
            int d = dt * 32 + (r & 3) + 8 * (r >> 2) + 4 * half;
            smem[(wave * 32 + l31) * 72 + d] = f2bf(o[dt][r] * inv);
        }
    __syncthreads();
    #pragma unroll
    for (int i = 0; i < 4; i++) {
        int c = tid + 256 * i;
        int row = c >> 3;
        int ch = (c & 7) * 8;
        uint4 v = *(const uint4*)&smem[row * 72 + ch];
        *(uint4*)&outb[(size_t)(b * SEQ + qt * 128 + row) * EMB + h * 64 + ch] = v;
    }
}

extern "C" void kernel_launch(void* const* d_in, const int* in_sizes, int n_in,
                              void* d_out, int out_size, void* d_ws, size_t ws_size,
                              hipStream_t stream) {
    const float* X     = (const float*)d_in[0];
    const float* Wqkv  = (const float*)d_in[1];
    const float* bqkv  = (const float*)d_in[2];
    const float* Wproj = (const float*)d_in[3];
    const float* bproj = (const float*)d_in[4];
    float* out = (float*)d_out;

    char* ws = (char*)d_ws;
    unsigned short* Xb     = (unsigned short*)(ws);                // 16,777,216 B
    unsigned short* WqkvT  = (unsigned short*)(ws + 16777216);     //  6,291,456 B
    unsigned short* WprojT = (unsigned short*)(ws + 23068672);     //  2,097,152 B
    unsigned short* qkvb   = (unsigned short*)(ws + 25165824);     // 50,331,648 B
    unsigned short* Vt     = (unsigned short*)(ws + 75497472);     // 16,777,216 B
    unsigned short* attnb  = (unsigned short*)(ws + 92274688);     // 16,777,216 B

    cvt_bf16<<<2048, 256, 0, stream>>>((const float4*)X, (ushort4*)Xb, (4 * 2048 * 1024) / 4);
    transpose_cvt<<<dim3(3072 / 32, 1024 / 32), 256, 0, stream>>>(Wqkv, WqkvT, 1024, 3072);
    transpose_cvt<<<dim3(1024 / 32, 1024 / 32), 256, 0, stream>>>(Wproj, WprojT, 1024, 1024);
    gemm_bf16<true><<<dim3(3072 / BN, 8192 / BM), 256, 0, stream>>>(
        Xb, WqkvT, bqkv, qkvb, 8192, 3072, 1024);
    transpose_v<<<dim3(32, 64), 256, 0, stream>>>(qkvb, Vt);
    attention<<<dim3(16, 64), 256, 0, stream>>>(qkvb, Vt, attnb);
    gemm_bf16<false><<<dim3(1024 / BN, 8192 / BM), 256, 0, stream>>>(
        attnb, WprojT, bproj, out, 8192, 1024, 1024);
}

// Round 4
// 300.277 us; speedup vs baseline: 34.4464x; 1.1134x over previous
//
#include <hip/hip_runtime.h>
#include <hip/hip_bf16.h>

#define EMB 1024
#define SEQ 2048
#define ATT_SCALE 0.18033688011112042f  // 0.125 * log2(e)

typedef __bf16 bf16x8 __attribute__((ext_vector_type(8)));
typedef float f32x4 __attribute__((ext_vector_type(4)));
typedef float f32x16 __attribute__((ext_vector_type(16)));

__device__ __forceinline__ unsigned short f2bf(float f) {
    union { float f; unsigned int u; } v; v.f = f;
    unsigned int r = (v.u + 0x7FFFu + ((v.u >> 16) & 1u)) >> 16;
    return (unsigned short)r;
}

__device__ __forceinline__ void async_load16(const void* g, void* l) {
    __builtin_amdgcn_global_load_lds(
        (const __attribute__((address_space(1))) unsigned int*)g,
        (__attribute__((address_space(3))) unsigned int*)l, 16, 0, 0);
}

// ---------------- fp32 -> bf16 elementwise ----------------
__global__ void cvt_bf16(const float4* __restrict__ in, ushort4* __restrict__ out, int n4) {
    int i = blockIdx.x * blockDim.x + threadIdx.x;
    int stride = gridDim.x * blockDim.x;
    for (; i < n4; i += stride) {
        float4 v = in[i];
        ushort4 o;
        o.x = f2bf(v.x); o.y = f2bf(v.y); o.z = f2bf(v.z); o.w = f2bf(v.w);
        out[i] = o;
    }
}

// ---------------- transpose + convert: in [R][C] f32 -> out [C][R] bf16 ----------------
__global__ void transpose_cvt(const float* __restrict__ in, unsigned short* __restrict__ out,
                              int R, int C) {
    __shared__ float tile[32][33];
    int bx = blockIdx.x * 32;
    int by = blockIdx.y * 32;
    int tx = threadIdx.x & 31;
    int ty = threadIdx.x >> 5;
    #pragma unroll
    for (int i = 0; i < 32; i += 8)
        tile[ty + i][tx] = in[(size_t)(by + ty + i) * C + bx + tx];
    __syncthreads();
    #pragma unroll
    for (int i = 0; i < 32; i += 8)
        out[(size_t)(bx + ty + i) * R + by + tx] = f2bf(tile[tx][ty + i]);
}

// ---------------- bf16 MFMA GEMM (m97 structure): C[M,N] = A * Bt^T + bias ----------------
// global_load_lds width-16 staging, XOR-swizzled chunk order, unpadded pitch-64 LDS.
#define BM 128
#define BN 128
#define BK 64

template<bool OUT_BF16>
__global__ __launch_bounds__(256, 2)
void gemm_bf16(const unsigned short* __restrict__ A,
               const unsigned short* __restrict__ Bt,
               const float* __restrict__ bias,
               void* __restrict__ Cout,
               int M, int N, int K) {
    __shared__ unsigned short As[BM * 64];
    __shared__ unsigned short Bs[BN * 64];
    const int tid = threadIdx.x;
    const int m0 = blockIdx.y * BM;
    const int n0 = blockIdx.x * BN;
    const int lane = tid & 63;
    const int wave = tid >> 6;
    const int wm = (wave & 1) * 64;
    const int wn = (wave >> 1) * 64;
    const int lm = lane & 15;
    const int quad = lane >> 4;
    const int r8 = lane >> 3;    // 0..7 row within 8-row staging group
    const int pc = lane & 7;     // phys chunk

    f32x4 acc[4][4] = {};

    for (int k0 = 0; k0 < K; k0 += BK) {
        __syncthreads();
        // async stage: each wave 32 rows of A and B; LDS[r][pc] = G[r][pc ^ (r&7)]
        #pragma unroll
        for (int i = 0; i < 4; i++) {
            int r = wave * 32 + i * 8 + r8;
            int lc = pc ^ (r & 7);
            async_load16(&A[(size_t)(m0 + r) * K + k0 + lc * 8], &As[(wave * 32 + i * 8) * 64]);
            async_load16(&Bt[(size_t)(n0 + r) * K + k0 + lc * 8], &Bs[(wave * 32 + i * 8) * 64]);
        }
        __syncthreads();
        #pragma unroll
        for (int kk = 0; kk < 2; kk++) {
            bf16x8 af[4], bfr[4];
            #pragma unroll
            for (int t = 0; t < 4; t++) {
                int phys = ((kk * 4 + quad) ^ (lm & 7)) << 3;
                af[t]  = *(const bf16x8*)&As[(wm + t * 16 + lm) * 64 + phys];
                bfr[t] = *(const bf16x8*)&Bs[(wn + t * 16 + lm) * 64 + phys];
            }
            #pragma unroll
            for (int mt = 0; mt < 4; mt++)
                #pragma unroll
                for (int nt = 0; nt < 4; nt++)
                    acc[mt][nt] = __builtin_amdgcn_mfma_f32_16x16x32_bf16(
                        af[mt], bfr[nt], acc[mt][nt], 0, 0, 0);
        }
    }
    #pragma unroll
    for (int mt = 0; mt < 4; mt++) {
        #pragma unroll
        for (int nt = 0; nt < 4; nt++) {
            int col = n0 + wn + nt * 16 + lm;
            float bv = bias[col];
            #pragma unroll
            for (int r = 0; r < 4; r++) {
                int row = m0 + wm + mt * 16 + quad * 4 + r;
                float val = acc[mt][nt][r] + bv;
                if (OUT_BF16)
                    ((unsigned short*)Cout)[(size_t)row * N + col] = f2bf(val);
                else
                    ((float*)Cout)[(size_t)row * N + col] = val;
            }
        }
    }
}

// ---------------- V transpose: qkv bf16 [8192][3072] V-part -> Vt [B*H][64 d][2048 s] ----------------
__global__ void transpose_v(const unsigned short* __restrict__ qkv,
                            unsigned short* __restrict__ vt) {
    __shared__ unsigned short T[64 * 72];
    const int tid = threadIdx.x;
    const int sb = blockIdx.x;
    const int bh = blockIdx.y;
    const int b = bh >> 4;
    const int h = bh & 15;
    const unsigned short* src = qkv + (size_t)(b * SEQ + sb * 64) * 3072 + 2 * EMB + h * 64;
    #pragma unroll
    for (int i = 0; i < 2; i++) {
        int c = tid + 256 * i;
        int row = c >> 3;
        int col = (c & 7) * 8;
        *(uint4*)&T[row * 72 + col] = *(const uint4*)&src[(size_t)row * 3072 + col];
    }
    __syncthreads();
    unsigned short* dst = vt + (size_t)bh * 64 * SEQ + sb * 64;
    #pragma unroll
    for (int i = 0; i < 2; i++) {
        int c = tid + 256 * i;
        int dr = c >> 3;
        int sc = (c & 7) * 8;
        unsigned short tmp[8];
        #pragma unroll
        for (int j = 0; j < 8; j++) tmp[j] = T[(sc + j) * 72 + dr];
        *(uint4*)&dst[(size_t)dr * SEQ + sc] = *(uint4*)tmp;
    }
}

// ---------------- MFMA flash attention, S^T formulation ----------------
// grid (8 paired q-tiles, 64 b*h), 256 threads = 4 waves x 32 q-rows.
// Block processes qt=blockIdx.x then qt=15-blockIdx.x (equal total work).
// Register double-buffer: prefetch K/V tile kb+1 during compute of kb.
__global__ __launch_bounds__(256, 3)
void attention(const unsigned short* __restrict__ qkv,   // [8192][3072] bf16
               const unsigned short* __restrict__ vt,    // [64][64][2048] bf16
               unsigned short* __restrict__ outb) {      // [8192][1024] bf16
    __shared__ unsigned short smem[128 * 72];            // Ks | Vs, reused for epilogue
    unsigned short* Ks = smem;
    unsigned short* Vs = smem + 64 * 72;
    const int tid = threadIdx.x;
    const int lane = tid & 63;
    const int wave = tid >> 6;
    const int l31 = lane & 31;
    const int half = lane >> 5;
    const int bh = blockIdx.y;
    const int b = bh >> 4;
    const int h = bh & 15;
    // staging coords (per thread: 2 K chunks + 2 V chunks)
    const int srow0 = tid >> 3;           // rows for i=0 (c=tid)
    const int sch  = (tid & 7) * 8;

    for (int ph = 0; ph < 2; ph++) {
        const int qt = ph ? (15 - blockIdx.x) : blockIdx.x;
        const int qs = qt * 128 + wave * 32 + l31;
        const size_t qgrow = (size_t)b * SEQ + qs;

        // Q fragments (B operand): n=q=lane&31, k=d=16*dt+8*half+j
        bf16x8 qf[4];
        #pragma unroll
        for (int dt = 0; dt < 4; dt++)
            qf[dt] = *(const bf16x8*)&qkv[qgrow * 3072 + h * 64 + dt * 16 + half * 8];

        f32x16 o[2] = {};
        float m_prev = -1e30f, lsum = 0.f;

        const int nkb = 2 * qt + 2;
        const int qmax_w = qt * 128 + wave * 32 + 31;    // wave's max q row

        // prefetch kb=0
        uint4 kreg[2], vreg[2];
        #pragma unroll
        for (int i = 0; i < 2; i++) {
            int row = srow0 + 32 * i;
            kreg[i] = *(const uint4*)&qkv[(size_t)(b * SEQ + row) * 3072 + EMB + h * 64 + sch];
            vreg[i] = *(const uint4*)&vt[(size_t)(bh * 64 + row) * SEQ + sch];
        }

        for (int kb = 0; kb < nkb; kb++) {
            __syncthreads();   // previous readers (or prev phase epilogue) done
            #pragma unroll
            for (int i = 0; i < 2; i++) {
                int row = srow0 + 32 * i;
                *(uint4*)&Ks[row * 72 + sch] = kreg[i];
                *(uint4*)&Vs[row * 72 + sch] = vreg[i];
            }
            __syncthreads();
            // prefetch next tile (overlaps with compute below)
            if (kb + 1 < nkb) {
                #pragma unroll
                for (int i = 0; i < 2; i++) {
                    int row = srow0 + 32 * i;
                    kreg[i] = *(const uint4*)&qkv[(size_t)(b * SEQ + (kb + 1) * 64 + row) * 3072 + EMB + h * 64 + sch];
                    vreg[i] = *(const uint4*)&vt[(size_t)(bh * 64 + row) * SEQ + (kb + 1) * 64 + sch];
                }
            }

            if (kb * 64 > qmax_w) continue;   // fully masked for this wave

            // S^T = K Q^T : 2 c-tiles x 32 q
            f32x16 st[2] = {};
            #pragma unroll
            for (int dt = 0; dt < 4; dt++) {
                #pragma unroll
                for (int ct = 0; ct < 2; ct++) {
                    bf16x8 kf = *(const bf16x8*)&Ks[(ct * 32 + l31) * 72 + dt * 16 + half * 8];
                    st[ct] = __builtin_amdgcn_mfma_f32_32x32x16_bf16(kf, qf[dt], st[ct], 0, 0, 0);
                }
            }

            // causal mask (wave-uniform branch)
            if (kb * 64 + 63 > qt * 128 + wave * 32) {
                #pragma unroll
                for (int ct = 0; ct < 2; ct++)
                    #pragma unroll
                    for (int r = 0; r < 16; r++) {
                        int cg = kb * 64 + ct * 32 + (r & 3) + 8 * (r >> 2) + 4 * half;
                        if (cg > qs) st[ct][r] = -1e9f;
                    }
            }

            // online softmax, per-lane scalar state (q = lane&31)
            float mx = -1e30f;
            #pragma unroll
            for (int r = 0; r < 16; r++) mx = fmaxf(mx, fmaxf(st[0][r], st[1][r]));
            mx = fmaxf(mx, __shfl_xor(mx, 32, 64));
            float m_new = fmaxf(m_prev, mx);
            float alpha = exp2f((m_prev - m_new) * ATT_SCALE);
            float nmc = -m_new * ATT_SCALE;
            float sum = 0.f;
            #pragma unroll
            for (int r = 0; r < 16; r++) {
                st[0][r] = exp2f(__builtin_fmaf(st[0][r], ATT_SCALE, nmc));
                st[1][r] = exp2f(__builtin_fmaf(st[1][r], ATT_SCALE, nmc));
                sum += st[0][r] + st[1][r];
            }
            sum += __shfl_xor(sum, 32, 64);
            lsum = lsum * alpha + sum;
            m_prev = m_new;
            #pragma unroll
            for (int r = 0; r < 16; r++) { o[0][r] *= alpha; o[1][r] *= alpha; }

            // pack P to bf16 pairs
            unsigned int pk[2][8];
            #pragma unroll
            for (int t = 0; t < 2; t++)
                #pragma unroll
                for (int i = 0; i < 8; i++) {
                    __hip_bfloat162 pb = __float22bfloat162_rn(float2{st[t][2 * i], st[t][2 * i + 1]});
                    union { __hip_bfloat162 b; unsigned int u; } cv; cv.b = pb;
                    pk[t][i] = cv.u;
                }

            // P^T B-frags via half-wave exchange; O^T += V^T P^T
            #pragma unroll
            for (int kt = 0; kt < 4; kt++) {
                const int t = kt >> 1, e = kt & 1;
                unsigned int own0 = half ? pk[t][4 * e + 2] : pk[t][4 * e + 0];
                unsigned int own1 = half ? pk[t][4 * e + 3] : pk[t][4 * e + 1];
                unsigned int snd0 = half ? pk[t][4 * e + 0] : pk[t][4 * e + 2];
                unsigned int snd1 = half ? pk[t][4 * e + 1] : pk[t][4 * e + 3];
                unsigned int rcv0 = (unsigned int)__shfl_xor((int)snd0, 32, 64);
                unsigned int rcv1 = (unsigned int)__shfl_xor((int)snd1, 32, 64);
                union { uint4 u; bf16x8 v; } pf;
                pf.u.x = half ? rcv0 : own0;
                pf.u.y = half ? rcv1 : own1;
                pf.u.z = half ? own0 : rcv0;
                pf.u.w = half ? own1 : rcv1;
                #pragma unroll
                for (int dt = 0; dt < 2; dt++) {
                    bf16x8 vf = *(const bf16x8*)&Vs[(dt * 32 + l31) * 72 + kt * 16 + half * 8];
                    o[dt] = __builtin_amdgcn_mfma_f32_32x32x16_bf16(vf, pf.v, o[dt], 0, 0, 0);
                }
            }
        }

        // epilogue: O^T -> LDS [q][d] -> coalesced bf16 store
        __syncthreads();
        float inv = 1.0f / lsum;
        #pragma unroll
        for (int dt = 0; dt < 2; dt++)
            #pragma unroll
            for (int r = 0; r < 16; r++) {
                int d = dt * 32 + (r & 3) + 8 * (r >> 2) + 4 * half;
                smem[(wave * 32 + l31) * 72 + d] = f2bf(o[dt][r] * inv);
            }
        __syncthreads();
        #pragma unroll
        for (int i = 0; i < 4; i++) {
            int c = tid + 256 * i;
            int row = c >> 3;
            int ch = (c & 7) * 8;
            uint4 v = *(const uint4*)&smem[row * 72 + ch];
            *(uint4*)&outb[(size_t)(b * SEQ + qt * 128 + row) * EMB + h * 64 + ch] = v;
        }
    }
}

extern "C" void kernel_launch(void* const* d_in, const int* in_sizes, int n_in,
                              void* d_out, int out_size, void* d_ws, size_t ws_size,
                              hipStream_t stream) {
    const float* X     = (const float*)d_in[0];
    const float* Wqkv  = (const float*)d_in[1];
    const float* bqkv  = (const float*)d_in[2];
    const float* Wproj = (const float*)d_in[3];
    const float* bproj = (const float*)d_in[4];
    float* out = (float*)d_out;

    char* ws = (char*)d_ws;
    unsigned short* Xb     = (unsigned short*)(ws);                // 16,777,216 B
    unsigned short* WqkvT  = (unsigned short*)(ws + 16777216);     //  6,291,456 B
    unsigned short* WprojT = (unsigned short*)(ws + 23068672);     //  2,097,152 B
    unsigned short* qkvb   = (unsigned short*)(ws + 25165824);     // 50,331,648 B
    unsigned short* Vt     = (unsigned short*)(ws + 75497472);     // 16,777,216 B
    unsigned short* attnb  = (unsigned short*)(ws + 92274688);     // 16,777,216 B

    cvt_bf16<<<2048, 256, 0, stream>>>((const float4*)X, (ushort4*)Xb, (4 * 2048 * 1024) / 4);
    transpose_cvt<<<dim3(3072 / 32, 1024 / 32), 256, 0, stream>>>(Wqkv, WqkvT, 1024, 3072);
    transpose_cvt<<<dim3(1024 / 32, 1024 / 32), 256, 0, stream>>>(Wproj, WprojT, 1024, 1024);
    gemm_bf16<true><<<dim3(3072 / BN, 8192 / BM), 256, 0, stream>>>(
        Xb, WqkvT, bqkv, qkvb, 8192, 3072, 1024);
    transpose_v<<<dim3(32, 64), 256, 0, stream>>>(qkvb, Vt);
    attention<<<dim3(8, 64), 256, 0, stream>>>(qkvb, Vt, attnb);
    gemm_bf16<false><<<dim3(1024 / BN, 8192 / BM), 256, 0, stream>>>(
        attnb, WprojT, bproj, out, 8192, 1024, 1024);
}